// Round 1
// baseline (3042.963 us; speedup 1.0000x reference)
//
#include <hip/hip_runtime.h>
#include <hip/hip_bf16.h>

#define NN     14848      // nodes
#define NE     475136     // edges
#define NROI   116        // nodes per graph
#define NGRAPH 128        // graphs
#define EPG    3712       // edges per graph (116*32)
#define HID    64
#define HC     256
#define NEG    0.01f
#define NEGA   0.2f

__device__ __forceinline__ float leaky(float x, float s) { return x >= 0.f ? x : s * x; }

// monotonic uint encoding for float atomicMax
__device__ __forceinline__ unsigned fenc(float f) {
    unsigned u = __float_as_uint(f);
    return (u & 0x80000000u) ? ~u : (u | 0x80000000u);
}
__device__ __forceinline__ float fdec(unsigned k) {
    return (k & 0x80000000u) ? __uint_as_float(k ^ 0x80000000u) : __uint_as_float(~k);
}

// ---------------------------------------------------------------- embed
// h0[n,64] = leaky(concat(x[n,:116], gemb[node_group[n],:16]) @ W(132,64) + b)
__global__ __launch_bounds__(64) void k_embed(
    const float* __restrict__ x, const int* __restrict__ ng,
    const float* __restrict__ gemb, const float* __restrict__ W,
    const float* __restrict__ b, float* __restrict__ h0)
{
    const int n = blockIdx.x, c = threadIdx.x;
    __shared__ float in[132];
    for (int k = c; k < NROI; k += 64) in[k] = x[n * NROI + k];
    if (c < 16) in[NROI + c] = gemb[ng[n] * 16 + c];
    __syncthreads();
    float acc = b[c];
    #pragma unroll 4
    for (int k = 0; k < 132; k++) acc = fmaf(in[k], W[k * 64 + c], acc);
    h0[n * 64 + c] = leaky(acc, NEG);
}

// ---------------------------------------------------------------- GINE conv
// per-graph block; agg[dst] += relu(h0[src] + leaky(edge_attr@We_enc + be))
__global__ __launch_bounds__(256) void k_gine(
    const int* __restrict__ src, const int* __restrict__ dst,
    const float* __restrict__ ea, const float* __restrict__ We,
    const float* __restrict__ be, const float* __restrict__ h0,
    float* __restrict__ agg)
{
    const int g = blockIdx.x, tid = threadIdx.x;
    const int wave = tid >> 6, lane = tid & 63;
    __shared__ float agg_s[NROI * 64];
    for (int i = tid; i < NROI * 64; i += 256) agg_s[i] = 0.f;
    __syncthreads();
    const int e0 = g * EPG, nb = g * NROI;
    const float bec = be[lane];
    for (int i = wave; i < EPG; i += 4) {
        const int e = e0 + i;
        const int s = src[e], dl = dst[e] - nb;
        const float p0 = ea[e * 5 + 0], p1 = ea[e * 5 + 1], p2 = ea[e * 5 + 2],
                    p3 = ea[e * 5 + 3], p4 = ea[e * 5 + 4];
        float em = bec;
        em = fmaf(p0, We[0 * 64 + lane], em);
        em = fmaf(p1, We[1 * 64 + lane], em);
        em = fmaf(p2, We[2 * 64 + lane], em);
        em = fmaf(p3, We[3 * 64 + lane], em);
        em = fmaf(p4, We[4 * 64 + lane], em);
        em = leaky(em, NEG);
        float msg = h0[s * 64 + lane] + em;
        msg = fmaxf(msg, 0.f);
        atomicAdd(&agg_s[dl * 64 + lane], msg);
    }
    __syncthreads();
    for (int i = tid; i < NROI * 64; i += 256) agg[nb * 64 + i] = agg_s[i];
}

// ---------------------------------------------------------------- node MLP + LayerNorm
__global__ __launch_bounds__(64) void k_mlp_ln(
    const float* __restrict__ h0, const float* __restrict__ agg,
    const float* __restrict__ W1, const float* __restrict__ b1,
    const float* __restrict__ W2, const float* __restrict__ b2,
    const float* __restrict__ lg, const float* __restrict__ lb,
    float* __restrict__ hn)
{
    const int n = blockIdx.x, c = threadIdx.x;
    __shared__ float v[64], t[64];
    v[c] = h0[n * 64 + c] + agg[n * 64 + c];
    __syncthreads();
    float a = b1[c];
    #pragma unroll 8
    for (int k = 0; k < 64; k++) a = fmaf(v[k], W1[k * 64 + c], a);
    t[c] = leaky(a, NEG);
    __syncthreads();
    float o = b2[c];
    #pragma unroll 8
    for (int k = 0; k < 64; k++) o = fmaf(t[k], W2[k * 64 + c], o);
    o = leaky(o, NEG);
    // LayerNorm over 64 channels (one wave)
    float s = o;
    #pragma unroll
    for (int off = 32; off; off >>= 1) s += __shfl_xor(s, off);
    const float mu = s * (1.f / 64.f);
    const float d = o - mu;
    float s2 = d * d;
    #pragma unroll
    for (int off = 32; off; off >>= 1) s2 += __shfl_xor(s2, off);
    const float var = s2 * (1.f / 64.f);
    hn[n * 64 + c] = d * rsqrtf(var + 1e-5f) * lg[c] + lb[c];
}

// ---------------------------------------------------------------- xl/xr projections
// 8 nodes per block, 256 output channels per thread-column
template <int D>
__global__ __launch_bounds__(256) void k_xlxr(
    const float* __restrict__ hin, const float* __restrict__ Wl,
    const float* __restrict__ Wr, float* __restrict__ X, float* __restrict__ Y)
{
    const int c = threadIdx.x;
    const int n0 = blockIdx.x * 8;
    __shared__ float v[8][D];
    #pragma unroll
    for (int j = 0; j < 8; j++)
        for (int k = c; k < D; k += 256) v[j][k] = hin[(n0 + j) * D + k];
    __syncthreads();
    float aL[8] = {0, 0, 0, 0, 0, 0, 0, 0};
    float aR[8] = {0, 0, 0, 0, 0, 0, 0, 0};
    for (int k = 0; k < D; k++) {
        const float wl = Wl[k * HC + c], wr = Wr[k * HC + c];
        #pragma unroll
        for (int j = 0; j < 8; j++) {
            const float hv = v[j][k];
            aL[j] = fmaf(hv, wl, aL[j]);
            aR[j] = fmaf(hv, wr, aR[j]);
        }
    }
    #pragma unroll
    for (int j = 0; j < 8; j++) {
        X[(n0 + j) * HC + c] = aL[j];
        Y[(n0 + j) * HC + c] = aR[j];
    }
}

// ---------------------------------------------------------------- fused GATv2 edge pass
// one block per (graph, head): logits -> per-dst max -> exp / denom / numerator (LDS)
// writes pre-BN output V and per-channel sum/sumsq stat partials
__global__ __launch_bounds__(256) void k_gat_edge(
    const int* __restrict__ src, const int* __restrict__ dst,
    const float* __restrict__ ea, const float* __restrict__ We,
    const float* __restrict__ att, const float* __restrict__ bias,
    const float* __restrict__ X, const float* __restrict__ Y,
    float* __restrict__ V, float* __restrict__ stats)
{
    const int g = blockIdx.x >> 2, h = blockIdx.x & 3;
    const int tid = threadIdx.x, wave = tid >> 6, lane = tid & 63;
    __shared__ float logit_s[EPG];
    __shared__ float num_s[NROI * 64];
    __shared__ float den_s[NROI];
    __shared__ unsigned max_s[NROI];
    for (int i = tid; i < NROI * 64; i += 256) num_s[i] = 0.f;
    if (tid < NROI) { den_s[tid] = 0.f; max_s[tid] = 0u; }
    __syncthreads();
    const int e0 = g * EPG, nb = g * NROI;
    const int col = h * 64 + lane;
    const float attv = att[h * 64 + lane];
    // pass 1: logits + per-dst max
    for (int i = wave; i < EPG; i += 4) {
        const int e = e0 + i;
        const int s = src[e], d = dst[e];
        const float p0 = ea[e * 5 + 0], p1 = ea[e * 5 + 1], p2 = ea[e * 5 + 2],
                    p3 = ea[e * 5 + 3], p4 = ea[e * 5 + 4];
        float ep = p0 * We[0 * HC + col];
        ep = fmaf(p1, We[1 * HC + col], ep);
        ep = fmaf(p2, We[2 * HC + col], ep);
        ep = fmaf(p3, We[3 * HC + col], ep);
        ep = fmaf(p4, We[4 * HC + col], ep);
        float z = X[s * HC + col] + Y[d * HC + col] + ep;
        z = leaky(z, NEGA);
        float pr = z * attv;
        #pragma unroll
        for (int off = 32; off; off >>= 1) pr += __shfl_xor(pr, off);
        if (lane == 0) {
            logit_s[i] = pr;
            atomicMax(&max_s[d - nb], fenc(pr));
        }
    }
    __syncthreads();
    // pass 2: exp, denominator, weighted numerator
    for (int i = wave; i < EPG; i += 4) {
        const int e = e0 + i;
        const int s = src[e], dl = dst[e] - nb;
        const float m = fdec(max_s[dl]);
        const float ex = __expf(logit_s[i] - m);
        if (lane == 0) atomicAdd(&den_s[dl], ex);
        atomicAdd(&num_s[dl * 64 + lane], X[s * HC + col] * ex);
    }
    __syncthreads();
    // output + BN stat partials
    float ps = 0.f, ps2 = 0.f;
    const float bb = bias[col];
    for (int r = wave; r < NROI; r += 4) {
        const float vv = num_s[r * 64 + lane] / (den_s[r] + 1e-16f) + bb;
        V[(nb + r) * HC + col] = vv;
        ps += vv;
        ps2 += vv * vv;
    }
    __syncthreads();
    num_s[tid] = ps;
    num_s[256 + tid] = ps2;
    __syncthreads();
    if (tid < 64) {
        const float s1 = num_s[tid] + num_s[64 + tid] + num_s[128 + tid] + num_s[192 + tid];
        const float s2 = num_s[256 + tid] + num_s[320 + tid] + num_s[384 + tid] + num_s[448 + tid];
        atomicAdd(&stats[h * 64 + tid], s1);
        atomicAdd(&stats[256 + h * 64 + tid], s2);
    }
}

// ---------------------------------------------------------------- BatchNorm apply + leaky
__global__ __launch_bounds__(256) void k_bn_apply(
    const float* __restrict__ V, const float* __restrict__ stats,
    const float* __restrict__ bg, const float* __restrict__ bb,
    float* __restrict__ H)
{
    const int n = blockIdx.x, c = threadIdx.x;
    const float inv_n = 1.f / (float)NN;
    const float mu = stats[c] * inv_n;
    float var = stats[256 + c] * inv_n - mu * mu;
    var = fmaxf(var, 0.f);
    const float vv = V[n * HC + c];
    const float o = (vv - mu) * rsqrtf(var + 1e-5f) * bg[c] + bb[c];
    H[n * HC + c] = leaky(o, NEG);
}

// ---------------------------------------------------------------- mean-pool + classifier
__global__ __launch_bounds__(256) void k_pool_fc(
    const float* __restrict__ H, const float* __restrict__ fW,
    const float* __restrict__ fb, float* __restrict__ out)
{
    const int g = blockIdx.x, c = threadIdx.x;
    float s = 0.f;
    for (int r = 0; r < NROI; r++) s += H[(g * NROI + r) * HC + c];
    s *= (1.f / (float)NROI);
    __shared__ float red[256];
    for (int o = 0; o < 2; o++) {
        red[c] = s * fW[c * 2 + o];
        __syncthreads();
        for (int off = 128; off; off >>= 1) {
            if (c < off) red[c] += red[c + off];
            __syncthreads();
        }
        if (c == 0) out[g * 2 + o] = red[0] + fb[o];
        __syncthreads();
    }
}

extern "C" void kernel_launch(void* const* d_in, const int* in_sizes, int n_in,
                              void* d_out, int out_size, void* d_ws, size_t ws_size,
                              hipStream_t stream) {
    const float* x         = (const float*)d_in[0];
    const int*   edge_idx  = (const int*)d_in[1];
    const float* edge_attr = (const float*)d_in[2];
    // d_in[3] = batch (implicit: 116 nodes/graph)
    const int*   node_grp  = (const int*)d_in[4];
    const float* group_emb = (const float*)d_in[5];
    const float* W_embed   = (const float*)d_in[6];
    const float* b_embed   = (const float*)d_in[7];
    const float* We_enc    = (const float*)d_in[8];
    const float* be_enc    = (const float*)d_in[9];
    const float* W1        = (const float*)d_in[10];
    const float* b1        = (const float*)d_in[11];
    const float* W2        = (const float*)d_in[12];
    const float* b2        = (const float*)d_in[13];
    const float* ln_g      = (const float*)d_in[14];
    const float* ln_b      = (const float*)d_in[15];
    const float* l0_Wl     = (const float*)d_in[16];
    const float* l0_Wr     = (const float*)d_in[17];
    const float* l0_We     = (const float*)d_in[18];
    const float* l0_att    = (const float*)d_in[19];
    const float* l0_b      = (const float*)d_in[20];
    const float* l0_bn_g   = (const float*)d_in[21];
    const float* l0_bn_b   = (const float*)d_in[22];
    const float* l1_Wl     = (const float*)d_in[23];
    const float* l1_Wr     = (const float*)d_in[24];
    const float* l1_We     = (const float*)d_in[25];
    const float* l1_att    = (const float*)d_in[26];
    const float* l1_b      = (const float*)d_in[27];
    const float* l1_bn_g   = (const float*)d_in[28];
    const float* l1_bn_b   = (const float*)d_in[29];
    const float* fc2_W     = (const float*)d_in[30];
    const float* fc2_b     = (const float*)d_in[31];

    const int* src = edge_idx;
    const int* dst = edge_idx + NE;

    float* ws    = (float*)d_ws;
    float* h0    = ws;                   // 64*NN
    float* agg   = h0 + 64 * NN;         // 64*NN
    float* hn    = agg + 64 * NN;        // 64*NN
    float* X     = hn + 64 * NN;         // 256*NN
    float* Y     = X + (size_t)HC * NN;  // 256*NN
    float* V     = Y + (size_t)HC * NN;  // 256*NN
    float* H     = V + (size_t)HC * NN;  // 256*NN
    float* stats = H + (size_t)HC * NN;  // 512

    float* out = (float*)d_out;

    k_embed<<<NN, 64, 0, stream>>>(x, node_grp, group_emb, W_embed, b_embed, h0);
    k_gine<<<NGRAPH, 256, 0, stream>>>(src, dst, edge_attr, We_enc, be_enc, h0, agg);
    k_mlp_ln<<<NN, 64, 0, stream>>>(h0, agg, W1, b1, W2, b2, ln_g, ln_b, hn);

    // GAT layer 0
    k_xlxr<64><<<NN / 8, 256, 0, stream>>>(hn, l0_Wl, l0_Wr, X, Y);
    hipMemsetAsync(stats, 0, 512 * sizeof(float), stream);
    k_gat_edge<<<NGRAPH * 4, 256, 0, stream>>>(src, dst, edge_attr, l0_We, l0_att,
                                               l0_b, X, Y, V, stats);
    k_bn_apply<<<NN, 256, 0, stream>>>(V, stats, l0_bn_g, l0_bn_b, H);

    // GAT layer 1
    k_xlxr<256><<<NN / 8, 256, 0, stream>>>(H, l1_Wl, l1_Wr, X, Y);
    hipMemsetAsync(stats, 0, 512 * sizeof(float), stream);
    k_gat_edge<<<NGRAPH * 4, 256, 0, stream>>>(src, dst, edge_attr, l1_We, l1_att,
                                               l1_b, X, Y, V, stats);
    k_bn_apply<<<NN, 256, 0, stream>>>(V, stats, l1_bn_g, l1_bn_b, H);

    k_pool_fc<<<NGRAPH, 256, 0, stream>>>(H, fc2_W, fc2_b, out);
}

// Round 2
// 668.665 us; speedup vs baseline: 4.5508x; 4.5508x over previous
//
#include <hip/hip_runtime.h>
#include <hip/hip_bf16.h>

#define NN     14848      // nodes
#define NE     475136     // edges
#define NROI   116        // nodes per graph
#define NGRAPH 128        // graphs
#define EPG    3712       // edges per graph (116*32)
#define HID    64
#define HC     256
#define NEG    0.01f
#define NEGA   0.2f

__device__ __forceinline__ float leaky(float x, float s) { return x >= 0.f ? x : s * x; }

// ---------------------------------------------------------------- embed
// h0[n,64] = leaky(concat(x[n,:116], gemb[node_group[n],:16]) @ W(132,64) + b)
__global__ __launch_bounds__(64) void k_embed(
    const float* __restrict__ x, const int* __restrict__ ng,
    const float* __restrict__ gemb, const float* __restrict__ W,
    const float* __restrict__ b, float* __restrict__ h0)
{
    const int n = blockIdx.x, c = threadIdx.x;
    __shared__ float in[132];
    for (int k = c; k < NROI; k += 64) in[k] = x[n * NROI + k];
    if (c < 16) in[NROI + c] = gemb[ng[n] * 16 + c];
    __syncthreads();
    float acc = b[c];
    #pragma unroll 4
    for (int k = 0; k < 132; k++) acc = fmaf(in[k], W[k * 64 + c], acc);
    h0[n * 64 + c] = leaky(acc, NEG);
}

// ---------------------------------------------------------------- CSR build (counting sort by dst, per graph)
// also pre-gathers edge_attr into sorted order (ea_s)
__global__ __launch_bounds__(256) void k_csr(
    const int* __restrict__ src, const int* __restrict__ dst,
    const float* __restrict__ ea,
    int* __restrict__ row_start, int* __restrict__ row_cnt,
    int* __restrict__ ssrc, float* __restrict__ ea_s)
{
    const int g = blockIdx.x, tid = threadIdx.x;
    const int e0 = g * EPG, nb = g * NROI;
    __shared__ int cnt[NROI], start[NROI], cur[NROI];
    if (tid < NROI) cnt[tid] = 0;
    __syncthreads();
    for (int i = tid; i < EPG; i += 256) atomicAdd(&cnt[dst[e0 + i] - nb], 1);
    __syncthreads();
    if (tid == 0) {
        int s = 0;
        for (int r = 0; r < NROI; r++) { start[r] = s; s += cnt[r]; }
    }
    __syncthreads();
    if (tid < NROI) {
        row_start[nb + tid] = e0 + start[tid];
        row_cnt[nb + tid] = cnt[tid];
        cur[tid] = start[tid];
    }
    __syncthreads();
    for (int i = tid; i < EPG; i += 256) {
        const int e = e0 + i, dl = dst[e] - nb;
        const int pos = atomicAdd(&cur[dl], 1);
        const int gi = e0 + pos;
        ssrc[gi] = src[e];
        #pragma unroll
        for (int k = 0; k < 5; k++) ea_s[gi * 5 + k] = ea[e * 5 + k];
    }
}

// ---------------------------------------------------------------- GINE (CSR, per-row wave) fused with MLP + LayerNorm
__global__ __launch_bounds__(256) void k_gine_mlp_ln(
    const float* __restrict__ h0, const int* __restrict__ row_start,
    const int* __restrict__ row_cnt, const int* __restrict__ ssrc,
    const float* __restrict__ ea_s,
    const float* __restrict__ We, const float* __restrict__ be,
    const float* __restrict__ W1, const float* __restrict__ b1,
    const float* __restrict__ W2, const float* __restrict__ b2,
    const float* __restrict__ lg, const float* __restrict__ lb,
    float* __restrict__ hn)
{
    const int tid = threadIdx.x, w = tid >> 6, lane = tid & 63;
    const int row = blockIdx.x * 4 + w;
    const int st = row_start[row], cnt = row_cnt[row];
    const float w0 = We[lane], w1 = We[64 + lane], w2 = We[128 + lane],
                w3 = We[192 + lane], w4 = We[256 + lane];
    const float bec = be[lane];
    float aggv = 0.f;
    for (int j = 0; j < cnt; j++) {
        const int idx = st + j;
        const int s = ssrc[idx];
        const float p0 = ea_s[idx * 5], p1 = ea_s[idx * 5 + 1], p2 = ea_s[idx * 5 + 2],
                    p3 = ea_s[idx * 5 + 3], p4 = ea_s[idx * 5 + 4];
        float em = bec;
        em = fmaf(p0, w0, em); em = fmaf(p1, w1, em); em = fmaf(p2, w2, em);
        em = fmaf(p3, w3, em); em = fmaf(p4, w4, em);
        em = leaky(em, NEG);
        aggv += fmaxf(h0[s * 64 + lane] + em, 0.f);
    }
    __shared__ float v[4][64], t[4][64];
    v[w][lane] = h0[row * 64 + lane] + aggv;
    __syncthreads();
    float a = b1[lane];
    #pragma unroll 8
    for (int k = 0; k < 64; k++) a = fmaf(v[w][k], W1[k * 64 + lane], a);
    t[w][lane] = leaky(a, NEG);
    __syncthreads();
    float o = b2[lane];
    #pragma unroll 8
    for (int k = 0; k < 64; k++) o = fmaf(t[w][k], W2[k * 64 + lane], o);
    o = leaky(o, NEG);
    float s = o;
    #pragma unroll
    for (int off = 32; off; off >>= 1) s += __shfl_xor(s, off);
    const float mu = s * (1.f / 64.f);
    const float d = o - mu;
    float s2 = d * d;
    #pragma unroll
    for (int off = 32; off; off >>= 1) s2 += __shfl_xor(s2, off);
    hn[row * 64 + lane] = d * rsqrtf(s2 * (1.f / 64.f) + 1e-5f) * lg[lane] + lb[lane];
}

// ---------------------------------------------------------------- xl/xr projections
// 8 nodes per block, 256 output channels per thread-column
template <int D>
__global__ __launch_bounds__(256) void k_xlxr(
    const float* __restrict__ hin, const float* __restrict__ Wl,
    const float* __restrict__ Wr, float* __restrict__ X, float* __restrict__ Y)
{
    const int c = threadIdx.x;
    const int n0 = blockIdx.x * 8;
    __shared__ float v[8][D];
    #pragma unroll
    for (int j = 0; j < 8; j++)
        for (int k = c; k < D; k += 256) v[j][k] = hin[(n0 + j) * D + k];
    __syncthreads();
    float aL[8] = {0, 0, 0, 0, 0, 0, 0, 0};
    float aR[8] = {0, 0, 0, 0, 0, 0, 0, 0};
    for (int k = 0; k < D; k++) {
        const float wl = Wl[k * HC + c], wr = Wr[k * HC + c];
        #pragma unroll
        for (int j = 0; j < 8; j++) {
            const float hv = v[j][k];
            aL[j] = fmaf(hv, wl, aL[j]);
            aR[j] = fmaf(hv, wr, aR[j]);
        }
    }
    #pragma unroll
    for (int j = 0; j < 8; j++) {
        X[(n0 + j) * HC + c] = aL[j];
        Y[(n0 + j) * HC + c] = aR[j];
    }
}

// ---------------------------------------------------------------- GATv2: one wave per (row, head), online softmax in registers
__global__ __launch_bounds__(256) void k_gat_row(
    const int* __restrict__ row_start, const int* __restrict__ row_cnt,
    const int* __restrict__ ssrc, const float* __restrict__ ea_s,
    const float* __restrict__ We, const float* __restrict__ att,
    const float* __restrict__ bias,
    const float* __restrict__ X, const float* __restrict__ Y,
    float* __restrict__ V)
{
    const int tid = threadIdx.x, h = tid >> 6, lane = tid & 63;
    const int row = blockIdx.x;
    const int col = h * 64 + lane;
    const int st = row_start[row], cnt = row_cnt[row];
    const float yv = Y[row * HC + col];
    const float attv = att[col];
    const float w0 = We[col], w1 = We[HC + col], w2 = We[2 * HC + col],
                w3 = We[3 * HC + col], w4 = We[4 * HC + col];
    float m = -INFINITY, den = 0.f, acc = 0.f;
    for (int j = 0; j < cnt; j++) {
        const int idx = st + j;
        const int s = ssrc[idx];
        const float p0 = ea_s[idx * 5], p1 = ea_s[idx * 5 + 1], p2 = ea_s[idx * 5 + 2],
                    p3 = ea_s[idx * 5 + 3], p4 = ea_s[idx * 5 + 4];
        float ep = p0 * w0;
        ep = fmaf(p1, w1, ep); ep = fmaf(p2, w2, ep);
        ep = fmaf(p3, w3, ep); ep = fmaf(p4, w4, ep);
        const float xv = X[s * HC + col];
        const float z = leaky(xv + yv + ep, NEGA);
        float pr = z * attv;
        #pragma unroll
        for (int off = 32; off; off >>= 1) pr += __shfl_xor(pr, off);
        const float mn = fmaxf(m, pr);
        const float sc = __expf(m - mn);     // first iter: exp(-inf)=0
        const float p = __expf(pr - mn);
        den = den * sc + p;
        acc = fmaf(acc, sc, xv * p);
        m = mn;
    }
    V[row * HC + col] = acc / (den + 1e-16f) + bias[col];
}

// ---------------------------------------------------------------- BN stats (sum / sumsq per channel)
__global__ __launch_bounds__(256) void k_bn_stats(
    const float* __restrict__ V, float* __restrict__ stats)
{
    const int c = threadIdx.x;
    const int r0 = blockIdx.x * NROI;
    float s1 = 0.f, s2 = 0.f;
    for (int r = 0; r < NROI; r++) {
        const float v = V[(r0 + r) * HC + c];
        s1 += v; s2 += v * v;
    }
    atomicAdd(&stats[c], s1);
    atomicAdd(&stats[256 + c], s2);
}

// ---------------------------------------------------------------- BatchNorm apply + leaky (in-place safe)
__global__ __launch_bounds__(256) void k_bn_apply(
    const float* __restrict__ V, const float* __restrict__ stats,
    const float* __restrict__ bg, const float* __restrict__ bb,
    float* __restrict__ H)
{
    const int n = blockIdx.x, c = threadIdx.x;
    const float inv_n = 1.f / (float)NN;
    const float mu = stats[c] * inv_n;
    float var = stats[256 + c] * inv_n - mu * mu;
    var = fmaxf(var, 0.f);
    const float vv = V[n * HC + c];
    const float o = (vv - mu) * rsqrtf(var + 1e-5f) * bg[c] + bb[c];
    H[n * HC + c] = leaky(o, NEG);
}

// ---------------------------------------------------------------- mean-pool + classifier
__global__ __launch_bounds__(256) void k_pool_fc(
    const float* __restrict__ H, const float* __restrict__ fW,
    const float* __restrict__ fb, float* __restrict__ out)
{
    const int g = blockIdx.x, c = threadIdx.x;
    float s = 0.f;
    for (int r = 0; r < NROI; r++) s += H[(g * NROI + r) * HC + c];
    s *= (1.f / (float)NROI);
    __shared__ float red[256];
    for (int o = 0; o < 2; o++) {
        red[c] = s * fW[c * 2 + o];
        __syncthreads();
        for (int off = 128; off; off >>= 1) {
            if (c < off) red[c] += red[c + off];
            __syncthreads();
        }
        if (c == 0) out[g * 2 + o] = red[0] + fb[o];
        __syncthreads();
    }
}

extern "C" void kernel_launch(void* const* d_in, const int* in_sizes, int n_in,
                              void* d_out, int out_size, void* d_ws, size_t ws_size,
                              hipStream_t stream) {
    const float* x         = (const float*)d_in[0];
    const int*   edge_idx  = (const int*)d_in[1];
    const float* edge_attr = (const float*)d_in[2];
    // d_in[3] = batch (implicit: 116 nodes/graph)
    const int*   node_grp  = (const int*)d_in[4];
    const float* group_emb = (const float*)d_in[5];
    const float* W_embed   = (const float*)d_in[6];
    const float* b_embed   = (const float*)d_in[7];
    const float* We_enc    = (const float*)d_in[8];
    const float* be_enc    = (const float*)d_in[9];
    const float* W1        = (const float*)d_in[10];
    const float* b1        = (const float*)d_in[11];
    const float* W2        = (const float*)d_in[12];
    const float* b2        = (const float*)d_in[13];
    const float* ln_g      = (const float*)d_in[14];
    const float* ln_b      = (const float*)d_in[15];
    const float* l0_Wl     = (const float*)d_in[16];
    const float* l0_Wr     = (const float*)d_in[17];
    const float* l0_We     = (const float*)d_in[18];
    const float* l0_att    = (const float*)d_in[19];
    const float* l0_b      = (const float*)d_in[20];
    const float* l0_bn_g   = (const float*)d_in[21];
    const float* l0_bn_b   = (const float*)d_in[22];
    const float* l1_Wl     = (const float*)d_in[23];
    const float* l1_Wr     = (const float*)d_in[24];
    const float* l1_We     = (const float*)d_in[25];
    const float* l1_att    = (const float*)d_in[26];
    const float* l1_b      = (const float*)d_in[27];
    const float* l1_bn_g   = (const float*)d_in[28];
    const float* l1_bn_b   = (const float*)d_in[29];
    const float* fc2_W     = (const float*)d_in[30];
    const float* fc2_b     = (const float*)d_in[31];

    const int* src = edge_idx;
    const int* dst = edge_idx + NE;

    float* ws    = (float*)d_ws;
    float* h0    = ws;                       // 64*NN
    float* hn    = h0 + (size_t)64 * NN;     // 64*NN
    float* X     = hn + (size_t)64 * NN;     // 256*NN
    float* Y     = X + (size_t)HC * NN;      // 256*NN
    float* V     = Y + (size_t)HC * NN;      // 256*NN (also holds H in-place)
    float* stats = V + (size_t)HC * NN;      // 512
    float* ea_s  = stats + 512;              // 5*NE
    int* row_start = (int*)(ea_s + (size_t)5 * NE);  // NN
    int* row_cnt   = row_start + NN;                 // NN
    int* ssrc      = row_cnt + NN;                   // NE

    float* out = (float*)d_out;

    k_embed<<<NN, 64, 0, stream>>>(x, node_grp, group_emb, W_embed, b_embed, h0);
    k_csr<<<NGRAPH, 256, 0, stream>>>(src, dst, edge_attr, row_start, row_cnt, ssrc, ea_s);
    k_gine_mlp_ln<<<NN / 4, 256, 0, stream>>>(h0, row_start, row_cnt, ssrc, ea_s,
                                              We_enc, be_enc, W1, b1, W2, b2, ln_g, ln_b, hn);

    // GAT layer 0
    k_xlxr<64><<<NN / 8, 256, 0, stream>>>(hn, l0_Wl, l0_Wr, X, Y);
    hipMemsetAsync(stats, 0, 512 * sizeof(float), stream);
    k_gat_row<<<NN, 256, 0, stream>>>(row_start, row_cnt, ssrc, ea_s,
                                      l0_We, l0_att, l0_b, X, Y, V);
    k_bn_stats<<<NGRAPH, 256, 0, stream>>>(V, stats);
    k_bn_apply<<<NN, 256, 0, stream>>>(V, stats, l0_bn_g, l0_bn_b, V);

    // GAT layer 1
    k_xlxr<256><<<NN / 8, 256, 0, stream>>>(V, l1_Wl, l1_Wr, X, Y);
    hipMemsetAsync(stats, 0, 512 * sizeof(float), stream);
    k_gat_row<<<NN, 256, 0, stream>>>(row_start, row_cnt, ssrc, ea_s,
                                      l1_We, l1_att, l1_b, X, Y, V);
    k_bn_stats<<<NGRAPH, 256, 0, stream>>>(V, stats);
    k_bn_apply<<<NN, 256, 0, stream>>>(V, stats, l1_bn_g, l1_bn_b, V);

    k_pool_fc<<<NGRAPH, 256, 0, stream>>>(V, fc2_W, fc2_b, out);
}

// Round 3
// 569.117 us; speedup vs baseline: 5.3468x; 1.1749x over previous
//
#include <hip/hip_runtime.h>
#include <hip/hip_bf16.h>

#define NN     14848      // nodes
#define NE     475136     // edges
#define NROI   116        // nodes per graph
#define NGRAPH 128        // graphs
#define EPG    3712       // edges per graph (116*32)
#define HID    64
#define HC     256
#define NEG    0.01f
#define NEGA   0.2f
#define EPB    2304       // max edges per half-graph block (mean 1856, +14 sigma)

__device__ __forceinline__ float leaky(float x, float s) { return x >= 0.f ? x : s * x; }

// ---------------------------------------------------------------- embed
__global__ __launch_bounds__(64) void k_embed(
    const float* __restrict__ x, const int* __restrict__ ng,
    const float* __restrict__ gemb, const float* __restrict__ W,
    const float* __restrict__ b, float* __restrict__ h0)
{
    const int n = blockIdx.x, c = threadIdx.x;
    __shared__ float in[132];
    for (int k = c; k < NROI; k += 64) in[k] = x[n * NROI + k];
    if (c < 16) in[NROI + c] = gemb[ng[n] * 16 + c];
    __syncthreads();
    float acc = b[c];
    #pragma unroll 4
    for (int k = 0; k < 132; k++) acc = fmaf(in[k], W[k * 64 + c], acc);
    h0[n * 64 + c] = leaky(acc, NEG);
}

// ---------------------------------------------------------------- CSR build (counting sort by dst, per graph)
// outputs: row_start (global edge idx), row_cnt, ssrc (global src id),
// sdst (LOCAL dst id), ea_s (edge_attr gathered, stride 8 for aligned float4)
__global__ __launch_bounds__(256) void k_csr(
    const int* __restrict__ src, const int* __restrict__ dst,
    const float* __restrict__ ea,
    int* __restrict__ row_start, int* __restrict__ row_cnt,
    int* __restrict__ ssrc, int* __restrict__ sdst, float* __restrict__ ea_s)
{
    const int g = blockIdx.x, tid = threadIdx.x;
    const int e0 = g * EPG, nb = g * NROI;
    __shared__ int cnt[NROI], start[NROI], cur[NROI];
    if (tid < NROI) cnt[tid] = 0;
    __syncthreads();
    for (int i = tid; i < EPG; i += 256) atomicAdd(&cnt[dst[e0 + i] - nb], 1);
    __syncthreads();
    if (tid == 0) {
        int s = 0;
        for (int r = 0; r < NROI; r++) { start[r] = s; s += cnt[r]; }
    }
    __syncthreads();
    if (tid < NROI) {
        row_start[nb + tid] = e0 + start[tid];
        row_cnt[nb + tid] = cnt[tid];
        cur[tid] = start[tid];
    }
    __syncthreads();
    for (int i = tid; i < EPG; i += 256) {
        const int e = e0 + i, dl = dst[e] - nb;
        const int pos = atomicAdd(&cur[dl], 1);
        const int gi = e0 + pos;
        ssrc[gi] = src[e];
        sdst[gi] = dl;
        #pragma unroll
        for (int k = 0; k < 5; k++) ea_s[(size_t)gi * 8 + k] = ea[e * 5 + k];
    }
}

// ---------------------------------------------------------------- GINE (CSR, per-row wave) fused with MLP + LayerNorm
__global__ __launch_bounds__(256) void k_gine_mlp_ln(
    const float* __restrict__ h0, const int* __restrict__ row_start,
    const int* __restrict__ row_cnt, const int* __restrict__ ssrc,
    const float* __restrict__ ea_s,
    const float* __restrict__ We, const float* __restrict__ be,
    const float* __restrict__ W1, const float* __restrict__ b1,
    const float* __restrict__ W2, const float* __restrict__ b2,
    const float* __restrict__ lg_, const float* __restrict__ lb_,
    float* __restrict__ hn)
{
    const int tid = threadIdx.x, w = tid >> 6, lane = tid & 63;
    const int row = blockIdx.x * 4 + w;
    const int st = row_start[row], cnt = row_cnt[row];
    const float w0 = We[lane], w1 = We[64 + lane], w2 = We[128 + lane],
                w3 = We[192 + lane], w4 = We[256 + lane];
    const float bec = be[lane];
    float aggv = 0.f;
    for (int j = 0; j < cnt; j++) {
        const int idx = st + j;
        const int s = ssrc[idx];
        const float4 q = *(const float4*)&ea_s[(size_t)idx * 8];
        const float q4 = ea_s[(size_t)idx * 8 + 4];
        float em = bec;
        em = fmaf(q.x, w0, em); em = fmaf(q.y, w1, em); em = fmaf(q.z, w2, em);
        em = fmaf(q.w, w3, em); em = fmaf(q4, w4, em);
        em = leaky(em, NEG);
        aggv += fmaxf(h0[s * 64 + lane] + em, 0.f);
    }
    __shared__ float v[4][64], t[4][64];
    v[w][lane] = h0[row * 64 + lane] + aggv;
    __syncthreads();
    float a = b1[lane];
    #pragma unroll 8
    for (int k = 0; k < 64; k++) a = fmaf(v[w][k], W1[k * 64 + lane], a);
    t[w][lane] = leaky(a, NEG);
    __syncthreads();
    float o = b2[lane];
    #pragma unroll 8
    for (int k = 0; k < 64; k++) o = fmaf(t[w][k], W2[k * 64 + lane], o);
    o = leaky(o, NEG);
    float s = o;
    #pragma unroll
    for (int off = 32; off; off >>= 1) s += __shfl_xor(s, off);
    const float mu = s * (1.f / 64.f);
    const float d = o - mu;
    float s2 = d * d;
    #pragma unroll
    for (int off = 32; off; off >>= 1) s2 += __shfl_xor(s2, off);
    hn[row * 64 + lane] = d * rsqrtf(s2 * (1.f / 64.f) + 1e-5f) * lg_[lane] + lb_[lane];
}

// ---------------------------------------------------------------- xl/xr projections: 16 nodes/block
template <int D>
__global__ __launch_bounds__(256) void k_xlxr(
    const float* __restrict__ hin, const float* __restrict__ Wl,
    const float* __restrict__ Wr, float* __restrict__ X, float* __restrict__ Y)
{
    const int c = threadIdx.x;
    const int n0 = blockIdx.x * 16;
    __shared__ float v[16][D];
    #pragma unroll
    for (int j = 0; j < 16; j++)
        for (int k = c; k < D; k += 256) v[j][k] = hin[(n0 + j) * D + k];
    __syncthreads();
    float aL[16], aR[16];
    #pragma unroll
    for (int j = 0; j < 16; j++) { aL[j] = 0.f; aR[j] = 0.f; }
    for (int k = 0; k < D; k++) {
        const float wl = Wl[k * HC + c], wr = Wr[k * HC + c];
        #pragma unroll
        for (int j = 0; j < 16; j++) {
            const float hv = v[j][k];
            aL[j] = fmaf(hv, wl, aL[j]);
            aR[j] = fmaf(hv, wr, aR[j]);
        }
    }
    #pragma unroll
    for (int j = 0; j < 16; j++) {
        X[(n0 + j) * HC + c] = aL[j];
        Y[(n0 + j) * HC + c] = aR[j];
    }
}

// ---------------------------------------------------------------- fused GATv2: lane=edge logits, LDS softmax, per-row numerator
// grid = NGRAPH * HEADS * 2; block = (graph g, head h, half of rows)
__global__ __launch_bounds__(256, 4) void k_gat(
    const int* __restrict__ row_start, const int* __restrict__ row_cnt,
    const int* __restrict__ ssrc, const int* __restrict__ sdst,
    const float* __restrict__ ea_s,
    const float* __restrict__ We, const float* __restrict__ att,
    const float* __restrict__ bias,
    const float* __restrict__ X, const float* __restrict__ Y,
    float* __restrict__ V)
{
    const int g = blockIdx.x >> 3;
    const int h = (blockIdx.x >> 1) & 3;
    const int half = blockIdx.x & 1;
    const int tid = threadIdx.x, w = tid >> 6, lane = tid & 63;
    const int nb = g * NROI, e0 = g * EPG, hc = h * 64;
    const int r0 = half * 58, r1 = r0 + 58;
    const int es = row_start[nb + r0];
    const int ee = (r1 < NROI) ? row_start[nb + r1] : e0 + EPG;

    __shared__ float Xs[NROI * 65];
    __shared__ float lg[EPB];

    // stage X head-slice: Xs[row][c], pad 65 to break bank aliasing
    for (int r = w; r < NROI; r += 4)
        Xs[r * 65 + lane] = X[(size_t)(nb + r) * HC + hc + lane];
    __syncthreads();

    // ---- phase A: logits, lane = edge (no cross-lane reduce)
    const int ne = ee - es;
    for (int i = tid; i < ne; i += 256) {
        const int e = es + i;
        const int sl = ssrc[e] - nb;
        const int dl = sdst[e];
        const float4 q = *(const float4*)&ea_s[(size_t)e * 8];
        const float q4 = ea_s[(size_t)e * 8 + 4];
        const float* yrow = &Y[(size_t)(nb + dl) * HC + hc];
        const int xb = sl * 65;
        float lacc = 0.f;
        #pragma unroll 8
        for (int c = 0; c < 64; c++) {
            float ep = q.x * We[0 * HC + hc + c];
            ep = fmaf(q.y, We[1 * HC + hc + c], ep);
            ep = fmaf(q.z, We[2 * HC + hc + c], ep);
            ep = fmaf(q.w, We[3 * HC + hc + c], ep);
            ep = fmaf(q4, We[4 * HC + hc + c], ep);
            const float z = Xs[xb + c] + yrow[c] + ep;
            lacc = fmaf(att[hc + c], leaky(z, NEGA), lacc);
        }
        lg[i] = lacc;
    }
    __syncthreads();

    // ---- phase B: per-row softmax (wave per row, lanes = edges)
    for (int r = r0 + w; r < r1; r += 4) {
        const int stl = row_start[nb + r] - es;
        const int cnt = row_cnt[nb + r];
        float m = -INFINITY;
        for (int j = lane; j < cnt; j += 64) m = fmaxf(m, lg[stl + j]);
        #pragma unroll
        for (int off = 32; off; off >>= 1) m = fmaxf(m, __shfl_xor(m, off));
        float s = 0.f;
        for (int j = lane; j < cnt; j += 64) {
            const float e_ = __expf(lg[stl + j] - m);
            lg[stl + j] = e_;
            s += e_;
        }
        #pragma unroll
        for (int off = 32; off; off >>= 1) s += __shfl_xor(s, off);
        const float inv = 1.f / (s + 1e-16f);
        for (int j = lane; j < cnt; j += 64) lg[stl + j] *= inv;
    }
    __syncthreads();

    // ---- phase C: numerator (wave per row, lane = channel)
    for (int r = r0 + w; r < r1; r += 4) {
        const int st = row_start[nb + r];
        const int cnt = row_cnt[nb + r];
        const int stl = st - es;
        float acc = 0.f;
        for (int j = 0; j < cnt; j++) {
            const int sl = ssrc[st + j] - nb;   // wave-uniform -> scalar load
            const float a = lg[stl + j];        // LDS broadcast
            acc = fmaf(Xs[sl * 65 + lane], a, acc);
        }
        V[(size_t)(nb + r) * HC + hc + lane] = acc + bias[hc + lane];
    }
}

// ---------------------------------------------------------------- BN stats (sum / sumsq per channel)
__global__ __launch_bounds__(256) void k_bn_stats(
    const float* __restrict__ V, float* __restrict__ stats)
{
    const int c = threadIdx.x;
    const int r0 = blockIdx.x * NROI;
    float s1 = 0.f, s2 = 0.f;
    for (int r = 0; r < NROI; r++) {
        const float v = V[(size_t)(r0 + r) * HC + c];
        s1 += v; s2 += v * v;
    }
    atomicAdd(&stats[c], s1);
    atomicAdd(&stats[256 + c], s2);
}

// ---------------------------------------------------------------- BatchNorm apply + leaky (in-place safe)
__global__ __launch_bounds__(256) void k_bn_apply(
    const float* __restrict__ V, const float* __restrict__ stats,
    const float* __restrict__ bg, const float* __restrict__ bb,
    float* __restrict__ H)
{
    const int n = blockIdx.x, c = threadIdx.x;
    const float inv_n = 1.f / (float)NN;
    const float mu = stats[c] * inv_n;
    float var = stats[256 + c] * inv_n - mu * mu;
    var = fmaxf(var, 0.f);
    const float vv = V[(size_t)n * HC + c];
    const float o = (vv - mu) * rsqrtf(var + 1e-5f) * bg[c] + bb[c];
    H[(size_t)n * HC + c] = leaky(o, NEG);
}

// ---------------------------------------------------------------- mean-pool + classifier
__global__ __launch_bounds__(256) void k_pool_fc(
    const float* __restrict__ H, const float* __restrict__ fW,
    const float* __restrict__ fb, float* __restrict__ out)
{
    const int g = blockIdx.x, c = threadIdx.x;
    float s = 0.f;
    for (int r = 0; r < NROI; r++) s += H[(size_t)(g * NROI + r) * HC + c];
    s *= (1.f / (float)NROI);
    __shared__ float red[256];
    for (int o = 0; o < 2; o++) {
        red[c] = s * fW[c * 2 + o];
        __syncthreads();
        for (int off = 128; off; off >>= 1) {
            if (c < off) red[c] += red[c + off];
            __syncthreads();
        }
        if (c == 0) out[g * 2 + o] = red[0] + fb[o];
        __syncthreads();
    }
}

extern "C" void kernel_launch(void* const* d_in, const int* in_sizes, int n_in,
                              void* d_out, int out_size, void* d_ws, size_t ws_size,
                              hipStream_t stream) {
    const float* x         = (const float*)d_in[0];
    const int*   edge_idx  = (const int*)d_in[1];
    const float* edge_attr = (const float*)d_in[2];
    const int*   node_grp  = (const int*)d_in[4];
    const float* group_emb = (const float*)d_in[5];
    const float* W_embed   = (const float*)d_in[6];
    const float* b_embed   = (const float*)d_in[7];
    const float* We_enc    = (const float*)d_in[8];
    const float* be_enc    = (const float*)d_in[9];
    const float* W1        = (const float*)d_in[10];
    const float* b1        = (const float*)d_in[11];
    const float* W2        = (const float*)d_in[12];
    const float* b2        = (const float*)d_in[13];
    const float* ln_g      = (const float*)d_in[14];
    const float* ln_b      = (const float*)d_in[15];
    const float* l0_Wl     = (const float*)d_in[16];
    const float* l0_Wr     = (const float*)d_in[17];
    const float* l0_We     = (const float*)d_in[18];
    const float* l0_att    = (const float*)d_in[19];
    const float* l0_b      = (const float*)d_in[20];
    const float* l0_bn_g   = (const float*)d_in[21];
    const float* l0_bn_b   = (const float*)d_in[22];
    const float* l1_Wl     = (const float*)d_in[23];
    const float* l1_Wr     = (const float*)d_in[24];
    const float* l1_We     = (const float*)d_in[25];
    const float* l1_att    = (const float*)d_in[26];
    const float* l1_b      = (const float*)d_in[27];
    const float* l1_bn_g   = (const float*)d_in[28];
    const float* l1_bn_b   = (const float*)d_in[29];
    const float* fc2_W     = (const float*)d_in[30];
    const float* fc2_b     = (const float*)d_in[31];

    const int* src = edge_idx;
    const int* dst = edge_idx + NE;

    float* ws    = (float*)d_ws;
    float* h0    = ws;                       // 64*NN
    float* hn    = h0 + (size_t)64 * NN;     // 64*NN
    float* X     = hn + (size_t)64 * NN;     // 256*NN
    float* Y     = X + (size_t)HC * NN;      // 256*NN
    float* V     = Y + (size_t)HC * NN;      // 256*NN (H in-place)
    float* stats = V + (size_t)HC * NN;      // 512
    float* ea_s  = stats + 512;              // 8*NE
    int* row_start = (int*)(ea_s + (size_t)8 * NE);  // NN
    int* row_cnt   = row_start + NN;                 // NN
    int* ssrc      = row_cnt + NN;                   // NE
    int* sdst      = ssrc + NE;                      // NE

    float* out = (float*)d_out;

    k_embed<<<NN, 64, 0, stream>>>(x, node_grp, group_emb, W_embed, b_embed, h0);
    k_csr<<<NGRAPH, 256, 0, stream>>>(src, dst, edge_attr, row_start, row_cnt, ssrc, sdst, ea_s);
    k_gine_mlp_ln<<<NN / 4, 256, 0, stream>>>(h0, row_start, row_cnt, ssrc, ea_s,
                                              We_enc, be_enc, W1, b1, W2, b2, ln_g, ln_b, hn);

    // GAT layer 0
    k_xlxr<64><<<NN / 16, 256, 0, stream>>>(hn, l0_Wl, l0_Wr, X, Y);
    hipMemsetAsync(stats, 0, 512 * sizeof(float), stream);
    k_gat<<<NGRAPH * 8, 256, 0, stream>>>(row_start, row_cnt, ssrc, sdst, ea_s,
                                          l0_We, l0_att, l0_b, X, Y, V);
    k_bn_stats<<<NGRAPH, 256, 0, stream>>>(V, stats);
    k_bn_apply<<<NN, 256, 0, stream>>>(V, stats, l0_bn_g, l0_bn_b, V);

    // GAT layer 1
    k_xlxr<256><<<NN / 16, 256, 0, stream>>>(V, l1_Wl, l1_Wr, X, Y);
    hipMemsetAsync(stats, 0, 512 * sizeof(float), stream);
    k_gat<<<NGRAPH * 8, 256, 0, stream>>>(row_start, row_cnt, ssrc, sdst, ea_s,
                                          l1_We, l1_att, l1_b, X, Y, V);
    k_bn_stats<<<NGRAPH, 256, 0, stream>>>(V, stats);
    k_bn_apply<<<NN, 256, 0, stream>>>(V, stats, l1_bn_g, l1_bn_b, V);

    k_pool_fc<<<NGRAPH, 256, 0, stream>>>(V, fc2_W, fc2_b, out);
}